// Round 3
// baseline (136.742 us; speedup 1.0000x reference)
//
#include <hip/hip_runtime.h>
#include <hip/hip_bf16.h>

#define NV     163842
#define KTOT   448                 // 7 neighbors * 64 feats
#define KQ     56                  // KTOT/8 : 16B k-octs
#define NT     ((NV + 31) / 32)    // 5121 32-row tiles
#define NWAVES 4096                // 512 blocks * 8 waves
#define XUNITS (NV * 64 / 8)       // 1,310,736 16B units of bf16-x
#define WQUADS (64 * KTOT / 4)     // 7,168 float4 quads of W
#define XB_BYTES ((size_t)NV * 64 * 2)   // 20,971,776
#define WB_BYTES (KQ * 64 * 16)          // 57,344

typedef __attribute__((ext_vector_type(8))) short bf16x8;
typedef __attribute__((ext_vector_type(4))) float f32x4;

__device__ __forceinline__ unsigned f2bf(float f) {
    unsigned u = __builtin_bit_cast(unsigned, f);
    return (u + 0x7FFFu + ((u >> 16) & 1u)) >> 16;   // RNE truncate to bf16
}
__device__ __forceinline__ unsigned pack2(float a, float b) {
    return f2bf(a) | (f2bf(b) << 16);
}

// ---- prep: x f32 -> bf16 rows; W f32 -> bf16 fragment layout (+bank swizzle);
//      zero the dynamic-tile counter ----
__global__ __launch_bounds__(256) void prep_kernel(
    const float* __restrict__ x, const float* __restrict__ W,
    unsigned char* __restrict__ ws)
{
    const int g = blockIdx.x * 256 + threadIdx.x;
    if (g < XUNITS) {
        const float4 lo = *reinterpret_cast<const float4*>(x + (size_t)g * 8);
        const float4 hi = *reinterpret_cast<const float4*>(x + (size_t)g * 8 + 4);
        uint4 u;
        u.x = pack2(lo.x, lo.y); u.y = pack2(lo.z, lo.w);
        u.z = pack2(hi.x, hi.y); u.w = pack2(hi.z, hi.w);
        *reinterpret_cast<uint4*>(ws + (size_t)g * 16) = u;
    } else if (g < XUNITS + WQUADS) {
        const int q = g - XUNITS;
        const int i = q << 2;              // i = o*448 + k, k%4==0
        const int o = i / KTOT;
        const int k = i - o * KTOT;
        const int kq = k >> 3;
        const int u = (kq << 6) + (o ^ ((kq & 3) << 1));
        const float4 w = *reinterpret_cast<const float4*>(W + i);
        uint2 p;
        p.x = pack2(w.x, w.y); p.y = pack2(w.z, w.w);
        *reinterpret_cast<uint2*>(ws + XB_BYTES + (size_t)u * 16 + (k & 7) * 2) = p;
    } else if (g == XUNITS + WQUADS) {
        *reinterpret_cast<int*>(ws + XB_BYTES + WB_BYTES) = 0;   // tile counter
    }
}

// ---- main GEMM: persistent waves, 32-row tiles, depth-4 gather pipeline ----
__global__ __launch_bounds__(512, 4) void conv_gemm3(
    const uint4* __restrict__ xb, const int* __restrict__ neigh,
    const uint4* __restrict__ Wb, const float* __restrict__ bias,
    float* __restrict__ out, int* __restrict__ counter)
{
    __shared__ uint4 Wl[KQ * 64];          // 57,344 B
    const int t = threadIdx.x;
    const int wave = t >> 6, lane = t & 63;
    const int l15 = lane & 15, lg = lane >> 4;

    int tile = blockIdx.x * 8 + wave;      // < 4096 always

    // prefetch first tile's neighbor indices before the staging barrier
    int idx0[7], idx1[7];
    {
        const int rb = tile * 32;
        int r0 = rb + l15;      r0 = r0 < NV ? r0 : NV - 1;
        int r1 = rb + 16 + l15; r1 = r1 < NV ? r1 : NV - 1;
        #pragma unroll
        for (int j = 0; j < 7; ++j) {
            idx0[j] = neigh[r0 * 7 + j];
            idx1[j] = neigh[r1 * 7 + j];
        }
    }

    for (int u = t; u < KQ * 64; u += 512) Wl[u] = Wb[u];
    __syncthreads();

    const int sl15 = l15 ^ (lg << 1);      // read-side of the W bank swizzle
    float bv[4];
    #pragma unroll
    for (int n = 0; n < 4; ++n) bv[n] = bias[(n << 4) + l15];

    while (true) {
        const int rowbase = tile * 32;

        f32x4 acc[2][4];
        #pragma unroll
        for (int m = 0; m < 2; ++m)
            #pragma unroll
            for (int n = 0; n < 4; ++n)
                acc[m][n] = (f32x4){0.f, 0.f, 0.f, 0.f};

        // step s = j*2+h, s in [0,14): lane's k-oct kq = s*4+lg
        uint4 pa[4], pb[4];
        #pragma unroll
        for (int s = 0; s < 4; ++s) {
            const int j = s >> 1, h = s & 1;
            pa[s] = xb[(size_t)idx0[j] * 8 + (h << 2) + lg];
            pb[s] = xb[(size_t)idx1[j] * 8 + (h << 2) + lg];
        }
        #pragma unroll
        for (int s = 0; s < 14; ++s) {
            const uint4 ca = pa[s & 3];
            const uint4 cb = pb[s & 3];
            if (s + 4 < 14) {
                const int s2 = s + 4, j = s2 >> 1, h = s2 & 1;
                pa[s & 3] = xb[(size_t)idx0[j] * 8 + (h << 2) + lg];
                pb[s & 3] = xb[(size_t)idx1[j] * 8 + (h << 2) + lg];
            }
            const int bbase = (((s << 2) + lg) << 6) + sl15;
            const bf16x8 A0 = __builtin_bit_cast(bf16x8, ca);
            const bf16x8 A1 = __builtin_bit_cast(bf16x8, cb);
            #pragma unroll
            for (int n = 0; n < 4; ++n) {
                const bf16x8 B = __builtin_bit_cast(bf16x8, Wl[bbase + (n << 4)]);
                acc[0][n] = __builtin_amdgcn_mfma_f32_16x16x32_bf16(A0, B, acc[0][n], 0, 0, 0);
                acc[1][n] = __builtin_amdgcn_mfma_f32_16x16x32_bf16(A1, B, acc[1][n], 0, 0, 0);
            }
        }

        // epilogue: D layout col=l15, row=(lane>>4)*4+r
        #pragma unroll
        for (int m = 0; m < 2; ++m) {
            const int rb = rowbase + (m << 4) + (lg << 2);
            #pragma unroll
            for (int r = 0; r < 4; ++r) {
                const int row = rb + r;
                if (row < NV) {
                    float* po = out + (size_t)row * 64 + l15;
                    #pragma unroll
                    for (int n = 0; n < 4; ++n)
                        po[n << 4] = acc[m][n][r] + bv[n];
                }
            }
        }

        // pull next tile (overflow region) dynamically
        int nt = 0;
        if (lane == 0) nt = atomicAdd(counter, 1);
        nt = __shfl(nt, 0) + NWAVES;
        if (nt >= NT) break;
        tile = nt;
        {
            const int rb = tile * 32;
            int r0 = rb + l15;      r0 = r0 < NV ? r0 : NV - 1;
            int r1 = rb + 16 + l15; r1 = r1 < NV ? r1 : NV - 1;
            #pragma unroll
            for (int j = 0; j < 7; ++j) {
                idx0[j] = neigh[r0 * 7 + j];
                idx1[j] = neigh[r1 * 7 + j];
            }
        }
    }
}

// ---- fallback (round-1 kernel) if ws is too small for the bf16 staging ----
__global__ __launch_bounds__(256) void conv_gemm_kernel(
    const float* __restrict__ x, const int* __restrict__ neigh,
    const float* __restrict__ W, const float* __restrict__ bias,
    float* __restrict__ out)
{
    __shared__ unsigned Wl[56 * 64 * 4];
    const int t = threadIdx.x;
    for (int g = t; g < (64 * KTOT) / 4; g += 256) {
        int i = g << 2;
        int o = i / KTOT;
        int k = i - o * KTOT;
        const float4 w = *reinterpret_cast<const float4*>(W + i);
        unsigned p0 = pack2(w.x, w.y);
        unsigned p1 = pack2(w.z, w.w);
        unsigned* dst = &Wl[((((k >> 3) << 6) + o) << 2) + ((k & 7) >> 1)];
        *reinterpret_cast<uint2*>(dst) = make_uint2(p0, p1);
    }
    __syncthreads();

    const int wave = t >> 6, lane = t & 63;
    const int l15 = lane & 15, lg = lane >> 4;
    const int rowbase = blockIdx.x * 128 + wave * 32;
    const int row0 = rowbase + l15;
    const int row1 = row0 + 16;
    const int r0c = row0 < NV ? row0 : NV - 1;
    const int r1c = row1 < NV ? row1 : NV - 1;

    int idx0[7], idx1[7];
    #pragma unroll
    for (int j = 0; j < 7; ++j) {
        idx0[j] = neigh[r0c * 7 + j];
        idx1[j] = neigh[r1c * 7 + j];
    }

    f32x4 acc[2][4];
    #pragma unroll
    for (int m = 0; m < 2; ++m)
        #pragma unroll
        for (int n = 0; n < 4; ++n)
            acc[m][n] = (f32x4){0.f, 0.f, 0.f, 0.f};

    for (int j = 0; j < 7; ++j) {
        const float* p0 = x + (size_t)idx0[j] * 64;
        const float* p1 = x + (size_t)idx1[j] * 64;
        #pragma unroll
        for (int h = 0; h < 2; ++h) {
            const int foff = (h << 5) + (lg << 3);
            float4 a0lo = *reinterpret_cast<const float4*>(p0 + foff);
            float4 a0hi = *reinterpret_cast<const float4*>(p0 + foff + 4);
            float4 a1lo = *reinterpret_cast<const float4*>(p1 + foff);
            float4 a1hi = *reinterpret_cast<const float4*>(p1 + foff + 4);
            union { unsigned u[4]; bf16x8 v; } A0, A1;
            A0.u[0] = pack2(a0lo.x, a0lo.y); A0.u[1] = pack2(a0lo.z, a0lo.w);
            A0.u[2] = pack2(a0hi.x, a0hi.y); A0.u[3] = pack2(a0hi.z, a0hi.w);
            A1.u[0] = pack2(a1lo.x, a1lo.y); A1.u[1] = pack2(a1lo.z, a1lo.w);
            A1.u[2] = pack2(a1hi.x, a1hi.y); A1.u[3] = pack2(a1hi.z, a1hi.w);
            const int kq = (((j << 1) + h) << 2) + lg;
            #pragma unroll
            for (int n = 0; n < 4; ++n) {
                bf16x8 B = *reinterpret_cast<const bf16x8*>(
                    &Wl[((kq << 6) + (n << 4) + l15) << 2]);
                acc[0][n] = __builtin_amdgcn_mfma_f32_16x16x32_bf16(A0.v, B, acc[0][n], 0, 0, 0);
                acc[1][n] = __builtin_amdgcn_mfma_f32_16x16x32_bf16(A1.v, B, acc[1][n], 0, 0, 0);
            }
        }
    }

    float bv[4];
    #pragma unroll
    for (int n = 0; n < 4; ++n) bv[n] = bias[(n << 4) + l15];

    #pragma unroll
    for (int m = 0; m < 2; ++m) {
        const int rb = rowbase + (m << 4) + (lg << 2);
        #pragma unroll
        for (int r = 0; r < 4; ++r) {
            const int row = rb + r;
            if (row < NV) {
                float* po = out + (size_t)row * 64 + l15;
                #pragma unroll
                for (int n = 0; n < 4; ++n)
                    po[n << 4] = acc[m][n][r] + bv[n];
            }
        }
    }
}

extern "C" void kernel_launch(void* const* d_in, const int* in_sizes, int n_in,
                              void* d_out, int out_size, void* d_ws, size_t ws_size,
                              hipStream_t stream) {
    const float* x     = (const float*)d_in[0];
    const int*   neigh = (const int*)d_in[1];
    const float* W     = (const float*)d_in[2];
    const float* b     = (const float*)d_in[3];
    float* out = (float*)d_out;

    if (ws_size >= XB_BYTES + WB_BYTES + sizeof(int)) {
        unsigned char* ws = (unsigned char*)d_ws;
        const int prep_blocks = (XUNITS + WQUADS + 1 + 255) / 256;
        prep_kernel<<<dim3(prep_blocks), dim3(256), 0, stream>>>(x, W, ws);
        const uint4* xb = (const uint4*)ws;
        const uint4* Wb = (const uint4*)(ws + XB_BYTES);
        int* counter = (int*)(ws + XB_BYTES + WB_BYTES);
        conv_gemm3<<<dim3(512), dim3(512), 0, stream>>>(xb, neigh, Wb, b, out, counter);
    } else {
        const int blocks = (NV + 127) / 128;   // 1281
        conv_gemm_kernel<<<dim3(blocks), dim3(256), 0, stream>>>(x, neigh, W, b, out);
    }
}

// Round 4
// 88.408 us; speedup vs baseline: 1.5467x; 1.5467x over previous
//
#include <hip/hip_runtime.h>
#include <hip/hip_bf16.h>

#define NV     163842
#define KTOT   448                 // 7 neighbors * 64 feats
#define KQ     56                  // KTOT/8 : 16B k-octs per W row
#define NT16   ((NV + 15) / 16)    // 10241 16-vertex tiles
#define GRID   1024                // 4 blocks/CU * 256 CU
#define XUNITS (NV * 64 / 8)       // 1,310,736 16B units of bf16-x
#define WQUADS (64 * KTOT / 4)     // 7,168 float4 quads of W
#define XB_BYTES ((size_t)NV * 64 * 2)   // 20,971,776
#define WB_BYTES (KQ * 64 * 16)          // 57,344

typedef __attribute__((ext_vector_type(8))) short bf16x8;
typedef __attribute__((ext_vector_type(4))) float f32x4;

__device__ __forceinline__ unsigned f2bf(float f) {
    unsigned u = __builtin_bit_cast(unsigned, f);
    return (u + 0x7FFFu + ((u >> 16) & 1u)) >> 16;   // RNE truncate to bf16
}
__device__ __forceinline__ unsigned pack2(float a, float b) {
    return f2bf(a) | (f2bf(b) << 16);
}

// ---- prep: x f32 -> bf16 rows; W f32 -> bf16 row-major octs [64][56] ----
__global__ __launch_bounds__(256) void prep_kernel(
    const float* __restrict__ x, const float* __restrict__ W,
    unsigned char* __restrict__ ws)
{
    const int g = blockIdx.x * 256 + threadIdx.x;
    if (g < XUNITS) {
        const float4 lo = *reinterpret_cast<const float4*>(x + (size_t)g * 8);
        const float4 hi = *reinterpret_cast<const float4*>(x + (size_t)g * 8 + 4);
        uint4 u;
        u.x = pack2(lo.x, lo.y); u.y = pack2(lo.z, lo.w);
        u.z = pack2(hi.x, hi.y); u.w = pack2(hi.z, hi.w);
        *reinterpret_cast<uint4*>(ws + (size_t)g * 16) = u;
    } else if (g < XUNITS + WQUADS) {
        const int q = g - XUNITS;
        const int i = q << 2;              // i = o*448 + k, k%4==0
        const int o = i / KTOT;
        const int k = i - o * KTOT;
        const int u = o * KQ + (k >> 3);   // oct index, row-major
        const float4 w = *reinterpret_cast<const float4*>(W + i);
        uint2 p;
        p.x = pack2(w.x, w.y); p.y = pack2(w.z, w.w);
        *reinterpret_cast<uint2*>(ws + XB_BYTES + (size_t)u * 16 + (k & 7) * 2) = p;
    }
}

// ---- main GEMM: A = W (regs), B = gathered x. Wave = one 16-wide o-quadrant.
// Block's 4 waves share one 16-vertex tile (shared gather addresses -> L1).
// D layout: col = lane&15 = vertex, row = (lane>>4)*4 + r = o_local.
__global__ __launch_bounds__(256, 4) void conv_gemm4(
    const uint4* __restrict__ xb, const int* __restrict__ neigh,
    const uint4* __restrict__ Wq, const float* __restrict__ bias,
    float* __restrict__ out)
{
    const int t = threadIdx.x;
    const int wave = t >> 6, lane = t & 63;
    const int l15 = lane & 15, lg = lane >> 4;
    const int orow = (wave << 4) + l15;        // this lane's W row (A row)

    // W fragments in registers: w[s] = W'[orow][k-oct s*4+lg], s=0..13
    uint4 w[14];
    #pragma unroll
    for (int s = 0; s < 14; ++s)
        w[s] = Wq[orow * KQ + (s << 2) + lg];

    const float4 bv = *reinterpret_cast<const float4*>(bias + (wave << 4) + (lg << 2));

    int idx[7];
    {
        int v = blockIdx.x * 16 + l15;
        int vc = v < NV ? v : NV - 1;
        #pragma unroll
        for (int j = 0; j < 7; ++j) idx[j] = neigh[vc * 7 + j];
    }

    for (int tile = blockIdx.x; tile < NT16; tile += GRID) {
        const int v = (tile << 4) + l15;

        f32x4 acc = (f32x4){0.f, 0.f, 0.f, 0.f};

        // depth-3 j-pipeline: 6 gathers in flight (constant-indexed slots)
        uint4 ga[3], gb[3];
        #pragma unroll
        for (int jp = 0; jp < 3; ++jp) {
            const uint4* p = xb + (size_t)idx[jp] * 8 + lg;
            ga[jp] = p[0];      // feats 0..31 oct lg
            gb[jp] = p[4];      // feats 32..63 oct lg
        }

        // prefetch next tile's neighbor indices (hidden under MFMAs)
        int nidx[7];
        const int ntile = tile + GRID;
        if (ntile < NT16) {
            int nv = (ntile << 4) + l15;
            int nvc = nv < NV ? nv : NV - 1;
            #pragma unroll
            for (int j = 0; j < 7; ++j) nidx[j] = neigh[nvc * 7 + j];
        }

        #pragma unroll
        for (int j = 0; j < 7; ++j) {
            const uint4 ca = ga[j % 3];
            const uint4 cb = gb[j % 3];
            if (j + 3 < 7) {
                const uint4* p = xb + (size_t)idx[j + 3] * 8 + lg;
                ga[j % 3] = p[0];
                gb[j % 3] = p[4];
            }
            const bf16x8 A0 = __builtin_bit_cast(bf16x8, w[2 * j]);
            const bf16x8 A1 = __builtin_bit_cast(bf16x8, w[2 * j + 1]);
            acc = __builtin_amdgcn_mfma_f32_16x16x32_bf16(A0, __builtin_bit_cast(bf16x8, ca), acc, 0, 0, 0);
            acc = __builtin_amdgcn_mfma_f32_16x16x32_bf16(A1, __builtin_bit_cast(bf16x8, cb), acc, 0, 0, 0);
        }

        if (v < NV) {
            float4 st;
            st.x = acc[0] + bv.x; st.y = acc[1] + bv.y;
            st.z = acc[2] + bv.z; st.w = acc[3] + bv.w;
            *reinterpret_cast<float4*>(out + (size_t)v * 64 + (wave << 4) + (lg << 2)) = st;
        }

        #pragma unroll
        for (int j = 0; j < 7; ++j) idx[j] = nidx[j];
    }
}

// ---- fallback (round-1 kernel) if ws is too small for the bf16 staging ----
__global__ __launch_bounds__(256) void conv_gemm_kernel(
    const float* __restrict__ x, const int* __restrict__ neigh,
    const float* __restrict__ W, const float* __restrict__ bias,
    float* __restrict__ out)
{
    __shared__ unsigned Wl[56 * 64 * 4];
    const int t = threadIdx.x;
    for (int g = t; g < (64 * KTOT) / 4; g += 256) {
        int i = g << 2;
        int o = i / KTOT;
        int k = i - o * KTOT;
        const float4 w = *reinterpret_cast<const float4*>(W + i);
        unsigned p0 = pack2(w.x, w.y);
        unsigned p1 = pack2(w.z, w.w);
        unsigned* dst = &Wl[((((k >> 3) << 6) + o) << 2) + ((k & 7) >> 1)];
        *reinterpret_cast<uint2*>(dst) = make_uint2(p0, p1);
    }
    __syncthreads();

    const int wave = t >> 6, lane = t & 63;
    const int l15 = lane & 15, lg = lane >> 4;
    const int rowbase = blockIdx.x * 128 + wave * 32;
    const int row0 = rowbase + l15;
    const int row1 = row0 + 16;
    const int r0c = row0 < NV ? row0 : NV - 1;
    const int r1c = row1 < NV ? row1 : NV - 1;

    int idx0[7], idx1[7];
    #pragma unroll
    for (int j = 0; j < 7; ++j) {
        idx0[j] = neigh[r0c * 7 + j];
        idx1[j] = neigh[r1c * 7 + j];
    }

    f32x4 acc[2][4];
    #pragma unroll
    for (int m = 0; m < 2; ++m)
        #pragma unroll
        for (int n = 0; n < 4; ++n)
            acc[m][n] = (f32x4){0.f, 0.f, 0.f, 0.f};

    for (int j = 0; j < 7; ++j) {
        const float* p0 = x + (size_t)idx0[j] * 64;
        const float* p1 = x + (size_t)idx1[j] * 64;
        #pragma unroll
        for (int h = 0; h < 2; ++h) {
            const int foff = (h << 5) + (lg << 3);
            float4 a0lo = *reinterpret_cast<const float4*>(p0 + foff);
            float4 a0hi = *reinterpret_cast<const float4*>(p0 + foff + 4);
            float4 a1lo = *reinterpret_cast<const float4*>(p1 + foff);
            float4 a1hi = *reinterpret_cast<const float4*>(p1 + foff + 4);
            union { unsigned u[4]; bf16x8 v; } A0, A1;
            A0.u[0] = pack2(a0lo.x, a0lo.y); A0.u[1] = pack2(a0lo.z, a0lo.w);
            A0.u[2] = pack2(a0hi.x, a0hi.y); A0.u[3] = pack2(a0hi.z, a0hi.w);
            A1.u[0] = pack2(a1lo.x, a1lo.y); A1.u[1] = pack2(a1lo.z, a1lo.w);
            A1.u[2] = pack2(a1hi.x, a1hi.y); A1.u[3] = pack2(a1hi.z, a1hi.w);
            const int kq = (((j << 1) + h) << 2) + lg;
            #pragma unroll
            for (int n = 0; n < 4; ++n) {
                bf16x8 B = *reinterpret_cast<const bf16x8*>(
                    &Wl[((kq << 6) + (n << 4) + l15) << 2]);
                acc[0][n] = __builtin_amdgcn_mfma_f32_16x16x32_bf16(A0.v, B, acc[0][n], 0, 0, 0);
                acc[1][n] = __builtin_amdgcn_mfma_f32_16x16x32_bf16(A1.v, B, acc[1][n], 0, 0, 0);
            }
        }
    }

    float bv[4];
    #pragma unroll
    for (int n = 0; n < 4; ++n) bv[n] = bias[(n << 4) + l15];

    #pragma unroll
    for (int m = 0; m < 2; ++m) {
        const int rb = rowbase + (m << 4) + (lg << 2);
        #pragma unroll
        for (int r = 0; r < 4; ++r) {
            const int row = rb + r;
            if (row < NV) {
                float* po = out + (size_t)row * 64 + l15;
                #pragma unroll
                for (int n = 0; n < 4; ++n)
                    po[n << 4] = acc[m][n][r] + bv[n];
            }
        }
    }
}

extern "C" void kernel_launch(void* const* d_in, const int* in_sizes, int n_in,
                              void* d_out, int out_size, void* d_ws, size_t ws_size,
                              hipStream_t stream) {
    const float* x     = (const float*)d_in[0];
    const int*   neigh = (const int*)d_in[1];
    const float* W     = (const float*)d_in[2];
    const float* b     = (const float*)d_in[3];
    float* out = (float*)d_out;

    if (ws_size >= XB_BYTES + WB_BYTES) {
        unsigned char* ws = (unsigned char*)d_ws;
        const int prep_blocks = (XUNITS + WQUADS + 255) / 256;
        prep_kernel<<<dim3(prep_blocks), dim3(256), 0, stream>>>(x, W, ws);
        const uint4* xb = (const uint4*)ws;
        const uint4* Wq = (const uint4*)(ws + XB_BYTES);
        conv_gemm4<<<dim3(GRID), dim3(256), 0, stream>>>(xb, neigh, Wq, b, out);
    } else {
        const int blocks = (NV + 127) / 128;   // 1281
        conv_gemm_kernel<<<dim3(blocks), dim3(256), 0, stream>>>(x, neigh, W, b, out);
    }
}

// Round 5
// 63.566 us; speedup vs baseline: 2.1512x; 1.3908x over previous
//
#include <hip/hip_runtime.h>
#include <hip/hip_bf16.h>

#define NV     163842
#define KTOT   448                 // 7 neighbors * 64 feats
#define KQ     56                  // KTOT/8 : 16B k-octs per W row
#define TV     32                  // verts per tile
#define ROWS   (TV * 7)            // 224 gathered rows per tile
#define NT32   ((NV + TV - 1) / TV)   // 5121 tiles
#define XUNITS (NV * 64 / 8)       // 1,310,736 16B units of bf16-x
#define WQUADS (64 * KTOT / 4)     // 7,168 float4 quads of W
#define XB_BYTES ((size_t)NV * 64 * 2)   // 20,971,776
#define WB_BYTES (KQ * 64 * 16)          // 57,344

typedef __attribute__((ext_vector_type(8))) short bf16x8;
typedef __attribute__((ext_vector_type(4))) float f32x4;

__device__ __forceinline__ unsigned f2bf(float f) {
    unsigned u = __builtin_bit_cast(unsigned, f);
    return (u + 0x7FFFu + ((u >> 16) & 1u)) >> 16;   // RNE truncate to bf16
}
__device__ __forceinline__ unsigned pack2(float a, float b) {
    return f2bf(a) | (f2bf(b) << 16);
}

// ---- prep: x f32 -> bf16 rows; W f32 -> bf16 row-major octs [64][56] ----
__global__ __launch_bounds__(256) void prep_kernel(
    const float* __restrict__ x, const float* __restrict__ W,
    unsigned char* __restrict__ ws)
{
    const int g = blockIdx.x * 256 + threadIdx.x;
    if (g < XUNITS) {
        const float4 lo = *reinterpret_cast<const float4*>(x + (size_t)g * 8);
        const float4 hi = *reinterpret_cast<const float4*>(x + (size_t)g * 8 + 4);
        uint4 u;
        u.x = pack2(lo.x, lo.y); u.y = pack2(lo.z, lo.w);
        u.z = pack2(hi.x, hi.y); u.w = pack2(hi.z, hi.w);
        *reinterpret_cast<uint4*>(ws + (size_t)g * 16) = u;
    } else if (g < XUNITS + WQUADS) {
        const int q = g - XUNITS;
        const int i = q << 2;              // i = o*448 + k, k%4==0
        const int o = i / KTOT;
        const int k = i - o * KTOT;
        const int u = o * KQ + (k >> 3);   // oct index, row-major
        const float4 w = *reinterpret_cast<const float4*>(W + i);
        uint2 p;
        p.x = pack2(w.x, w.y); p.y = pack2(w.z, w.w);
        *reinterpret_cast<uint2*>(ws + XB_BYTES + (size_t)u * 16 + (k & 7) * 2) = p;
    }
}

// ---- main GEMM: gather 224 x-rows into LDS (1 full 128B line per request),
// then MFMA with A = W (regs, 16 o-rows per wave), B = staged x (LDS).
// Block = 256 thr / 4 waves, one 32-vertex tile; wave w owns o in [16w,16w+16).
__global__ __launch_bounds__(256, 4) void conv_gemm5(
    const uint4* __restrict__ xb, const int* __restrict__ neigh,
    const uint4* __restrict__ Wq, const float* __restrict__ bias,
    float* __restrict__ out)
{
    __shared__ uint4 x_s[ROWS * 8];    // 28,672 B, oct XOR-swizzled by row
    __shared__ int   idx_s[ROWS];

    const int t = threadIdx.x;
    const int wave = t >> 6, lane = t & 63;
    const int l15 = lane & 15, lg = lane >> 4;
    const int base = blockIdx.x * TV;

    // W fragments for this wave's o-rows: s = j*2+h -> kq = 8j+4h+lg
    const int orow = (wave << 4) + l15;
    uint4 w[14];
    #pragma unroll
    for (int s = 0; s < 14; ++s)
        w[s] = Wq[orow * KQ + (s << 2) + lg];
    const float4 bv = *reinterpret_cast<const float4*>(bias + (wave << 4) + (lg << 2));

    // neighbor indices for the tile are flat-contiguous: neigh[base*7 .. +224)
    if (t < ROWS) {
        const int fi = base * 7 + t;
        idx_s[t] = neigh[fi < 7 * NV ? fi : 7 * NV - 1];
    }
    __syncthreads();

    // gather: 8 consecutive threads fetch one full 128B row (1 line request)
    #pragma unroll
    for (int it = 0; it < 7; ++it) {
        const int g = t + (it << 8);           // 0..1791 = 224 rows * 8 octs
        const int r = g >> 3, oct = g & 7;
        x_s[(r << 3) + (oct ^ (r & 7))] = xb[(size_t)idx_s[r] * 8 + oct];
    }
    __syncthreads();

    f32x4 acc[2];
    acc[0] = (f32x4){0.f, 0.f, 0.f, 0.f};
    acc[1] = (f32x4){0.f, 0.f, 0.f, 0.f};

    #pragma unroll
    for (int s = 0; s < 14; ++s) {
        const int j = s >> 1, h = s & 1;
        const bf16x8 A = __builtin_bit_cast(bf16x8, w[s]);
        #pragma unroll
        for (int m = 0; m < 2; ++m) {
            const int r = ((m << 4) + l15) * 7 + j;        // local row (vert,j)
            const int oct = ((h << 2) + lg) ^ (r & 7);     // swizzled oct
            const bf16x8 B = __builtin_bit_cast(bf16x8, x_s[(r << 3) + oct]);
            acc[m] = __builtin_amdgcn_mfma_f32_16x16x32_bf16(A, B, acc[m], 0, 0, 0);
        }
    }

    // D layout: col = l15 = vert(in group), row = lg*4 + reg = o_local
    #pragma unroll
    for (int m = 0; m < 2; ++m) {
        const int v = base + (m << 4) + l15;
        if (v < NV) {
            float4 st;
            st.x = acc[m][0] + bv.x; st.y = acc[m][1] + bv.y;
            st.z = acc[m][2] + bv.z; st.w = acc[m][3] + bv.w;
            *reinterpret_cast<float4*>(out + (size_t)v * 64 + (wave << 4) + (lg << 2)) = st;
        }
    }
}

// ---- fallback (round-1 kernel) if ws is too small for the bf16 staging ----
__global__ __launch_bounds__(256) void conv_gemm_kernel(
    const float* __restrict__ x, const int* __restrict__ neigh,
    const float* __restrict__ W, const float* __restrict__ bias,
    float* __restrict__ out)
{
    __shared__ unsigned Wl[56 * 64 * 4];
    const int t = threadIdx.x;
    for (int g = t; g < (64 * KTOT) / 4; g += 256) {
        int i = g << 2;
        int o = i / KTOT;
        int k = i - o * KTOT;
        const float4 w = *reinterpret_cast<const float4*>(W + i);
        unsigned p0 = pack2(w.x, w.y);
        unsigned p1 = pack2(w.z, w.w);
        unsigned* dst = &Wl[((((k >> 3) << 6) + o) << 2) + ((k & 7) >> 1)];
        *reinterpret_cast<uint2*>(dst) = make_uint2(p0, p1);
    }
    __syncthreads();

    const int wave = t >> 6, lane = t & 63;
    const int l15 = lane & 15, lg = lane >> 4;
    const int rowbase = blockIdx.x * 128 + wave * 32;
    const int row0 = rowbase + l15;
    const int row1 = row0 + 16;
    const int r0c = row0 < NV ? row0 : NV - 1;
    const int r1c = row1 < NV ? row1 : NV - 1;

    int idx0[7], idx1[7];
    #pragma unroll
    for (int j = 0; j < 7; ++j) {
        idx0[j] = neigh[r0c * 7 + j];
        idx1[j] = neigh[r1c * 7 + j];
    }

    f32x4 acc[2][4];
    #pragma unroll
    for (int m = 0; m < 2; ++m)
        #pragma unroll
        for (int n = 0; n < 4; ++n)
            acc[m][n] = (f32x4){0.f, 0.f, 0.f, 0.f};

    for (int j = 0; j < 7; ++j) {
        const float* p0 = x + (size_t)idx0[j] * 64;
        const float* p1 = x + (size_t)idx1[j] * 64;
        #pragma unroll
        for (int h = 0; h < 2; ++h) {
            const int foff = (h << 5) + (lg << 3);
            float4 a0lo = *reinterpret_cast<const float4*>(p0 + foff);
            float4 a0hi = *reinterpret_cast<const float4*>(p0 + foff + 4);
            float4 a1lo = *reinterpret_cast<const float4*>(p1 + foff);
            float4 a1hi = *reinterpret_cast<const float4*>(p1 + foff + 4);
            union { unsigned u[4]; bf16x8 v; } A0, A1;
            A0.u[0] = pack2(a0lo.x, a0lo.y); A0.u[1] = pack2(a0lo.z, a0lo.w);
            A0.u[2] = pack2(a0hi.x, a0hi.y); A0.u[3] = pack2(a0hi.z, a0hi.w);
            A1.u[0] = pack2(a1lo.x, a1lo.y); A1.u[1] = pack2(a1lo.z, a1lo.w);
            A1.u[2] = pack2(a1hi.x, a1hi.y); A1.u[3] = pack2(a1hi.z, a1hi.w);
            const int kq = (((j << 1) + h) << 2) + lg;
            #pragma unroll
            for (int n = 0; n < 4; ++n) {
                bf16x8 B = *reinterpret_cast<const bf16x8*>(
                    &Wl[((kq << 6) + (n << 4) + l15) << 2]);
                acc[0][n] = __builtin_amdgcn_mfma_f32_16x16x32_bf16(A0.v, B, acc[0][n], 0, 0, 0);
                acc[1][n] = __builtin_amdgcn_mfma_f32_16x16x32_bf16(A1.v, B, acc[1][n], 0, 0, 0);
            }
        }
    }

    float bv[4];
    #pragma unroll
    for (int n = 0; n < 4; ++n) bv[n] = bias[(n << 4) + l15];

    #pragma unroll
    for (int m = 0; m < 2; ++m) {
        const int rb = rowbase + (m << 4) + (lg << 2);
        #pragma unroll
        for (int r = 0; r < 4; ++r) {
            const int row = rb + r;
            if (row < NV) {
                float* po = out + (size_t)row * 64 + l15;
                #pragma unroll
                for (int n = 0; n < 4; ++n)
                    po[n << 4] = acc[m][n][r] + bv[n];
            }
        }
    }
}

extern "C" void kernel_launch(void* const* d_in, const int* in_sizes, int n_in,
                              void* d_out, int out_size, void* d_ws, size_t ws_size,
                              hipStream_t stream) {
    const float* x     = (const float*)d_in[0];
    const int*   neigh = (const int*)d_in[1];
    const float* W     = (const float*)d_in[2];
    const float* b     = (const float*)d_in[3];
    float* out = (float*)d_out;

    if (ws_size >= XB_BYTES + WB_BYTES) {
        unsigned char* ws = (unsigned char*)d_ws;
        const int prep_blocks = (XUNITS + WQUADS + 255) / 256;
        prep_kernel<<<dim3(prep_blocks), dim3(256), 0, stream>>>(x, W, ws);
        const uint4* xb = (const uint4*)ws;
        const uint4* Wq = (const uint4*)(ws + XB_BYTES);
        conv_gemm5<<<dim3(NT32), dim3(256), 0, stream>>>(xb, neigh, Wq, b, out);
    } else {
        const int blocks = (NV + 127) / 128;   // 1281
        conv_gemm_kernel<<<dim3(blocks), dim3(256), 0, stream>>>(x, neigh, W, b, out);
    }
}

// Round 6
// 44.624 us; speedup vs baseline: 3.0643x; 1.4245x over previous
//
#include <hip/hip_runtime.h>
#include <hip/hip_bf16.h>

#define NV     163842
#define KTOT   448                 // 7 neighbors * 64 feats
#define KQ     56                  // KTOT/8 : 16B k-octs
#define WTILES 5121                // 32-row wave-tiles
#define GRID6  512                 // blocks (2/CU), 768 thr each
#define XUNITS (NV * 64 / 8)       // 1,310,736 16B units of bf16-x
#define WQUADS (64 * KTOT / 4)     // 7,168 float4 quads of W
#define XB_BYTES ((size_t)NV * 64 * 2)   // 20,971,776
#define WB_BYTES (KQ * 64 * 16)          // 57,344

typedef __attribute__((ext_vector_type(8))) short bf16x8;
typedef __attribute__((ext_vector_type(4))) float f32x4;

__device__ __forceinline__ unsigned f2bf(float f) {
    unsigned u = __builtin_bit_cast(unsigned, f);
    return (u + 0x7FFFu + ((u >> 16) & 1u)) >> 16;   // RNE truncate to bf16
}
__device__ __forceinline__ unsigned pack2(float a, float b) {
    return f2bf(a) | (f2bf(b) << 16);
}

// ---- prep: x f32 -> bf16 rows; W f32 -> bf16 fragment layout (+bank swizzle) ----
// W element (o,k): kq=k>>3, stored at 16B-unit u = kq*64 + (o ^ ((kq&3)<<1)),
// halfword k&7.
__global__ __launch_bounds__(256) void prep_kernel(
    const float* __restrict__ x, const float* __restrict__ W,
    unsigned char* __restrict__ ws)
{
    const int g = blockIdx.x * 256 + threadIdx.x;
    if (g < XUNITS) {
        const float4 lo = *reinterpret_cast<const float4*>(x + (size_t)g * 8);
        const float4 hi = *reinterpret_cast<const float4*>(x + (size_t)g * 8 + 4);
        uint4 u;
        u.x = pack2(lo.x, lo.y); u.y = pack2(lo.z, lo.w);
        u.z = pack2(hi.x, hi.y); u.w = pack2(hi.z, hi.w);
        *reinterpret_cast<uint4*>(ws + (size_t)g * 16) = u;
    } else if (g < XUNITS + WQUADS) {
        const int q = g - XUNITS;
        const int i = q << 2;              // i = o*448 + k, k%4==0
        const int o = i / KTOT;
        const int k = i - o * KTOT;
        const int kq = k >> 3;
        const int u = (kq << 6) + (o ^ ((kq & 3) << 1));
        const float4 w = *reinterpret_cast<const float4*>(W + i);
        uint2 p;
        p.x = pack2(w.x, w.y); p.y = pack2(w.z, w.w);
        *reinterpret_cast<uint2*>(ws + XB_BYTES + (size_t)u * 16 + (k & 7) * 2) = p;
    }
}

// ---- main GEMM: 512 blocks x 768 thr (12 waves). Wave w of block b owns
// 32-row tile (b + 512*w) if < WTILES -> one balanced concurrent round.
// A = gathered x (direct per-lane 64B half-row loads), B = W from LDS.
__global__ __launch_bounds__(768, 6) void conv_gemm6(
    const uint4* __restrict__ xb, const int* __restrict__ neigh,
    const uint4* __restrict__ Wb, const float* __restrict__ bias,
    float* __restrict__ out)
{
    __shared__ uint4 Wl[KQ * 64];          // 57,344 B
    const int t = threadIdx.x;
    const int wave = t >> 6, lane = t & 63;
    const int l15 = lane & 15, lg = lane >> 4;

    const int tile = blockIdx.x + GRID6 * wave;
    const bool work = tile < WTILES;

    // prefetch this tile's neighbor indices before the staging barrier
    int idx0[7], idx1[7];
    if (work) {
        const int rb = tile * 32;
        int r0 = rb + l15;      r0 = r0 < NV ? r0 : NV - 1;
        int r1 = rb + 16 + l15; r1 = r1 < NV ? r1 : NV - 1;
        #pragma unroll
        for (int j = 0; j < 7; ++j) {
            idx0[j] = neigh[r0 * 7 + j];
            idx1[j] = neigh[r1 * 7 + j];
        }
    }

    for (int u = t; u < KQ * 64; u += 768) Wl[u] = Wb[u];
    __syncthreads();

    if (!work) return;

    const int sl15 = l15 ^ (lg << 1);      // read-side of the W bank swizzle
    const int rowbase = tile * 32;

    f32x4 acc[2][4];
    #pragma unroll
    for (int m = 0; m < 2; ++m)
        #pragma unroll
        for (int n = 0; n < 4; ++n)
            acc[m][n] = (f32x4){0.f, 0.f, 0.f, 0.f};

    #pragma unroll
    for (int j = 0; j < 7; ++j) {
        const uint4* p0 = xb + (size_t)idx0[j] * 8;   // bf16 row = 8 octs
        const uint4* p1 = xb + (size_t)idx1[j] * 8;
        uint4 a00 = p0[lg];       // feats 0..31, oct lg
        uint4 a01 = p0[4 + lg];   // feats 32..63
        uint4 a10 = p1[lg];
        uint4 a11 = p1[4 + lg];
        #pragma unroll
        for (int h = 0; h < 2; ++h) {
            const int kq = ((j * 2 + h) << 2) + lg;
            const int bbase = (kq << 6) + sl15;
            const bf16x8 A0 = __builtin_bit_cast(bf16x8, h ? a01 : a00);
            const bf16x8 A1 = __builtin_bit_cast(bf16x8, h ? a11 : a10);
            #pragma unroll
            for (int n = 0; n < 4; ++n) {
                const bf16x8 B = __builtin_bit_cast(bf16x8, Wl[bbase + (n << 4)]);
                acc[0][n] = __builtin_amdgcn_mfma_f32_16x16x32_bf16(A0, B, acc[0][n], 0, 0, 0);
                acc[1][n] = __builtin_amdgcn_mfma_f32_16x16x32_bf16(A1, B, acc[1][n], 0, 0, 0);
            }
        }
    }

    float bv[4];
    #pragma unroll
    for (int n = 0; n < 4; ++n) bv[n] = bias[(n << 4) + l15];

    // D layout: col = l15, row = lg*4 + r
    #pragma unroll
    for (int m = 0; m < 2; ++m) {
        const int rb = rowbase + (m << 4) + (lg << 2);
        #pragma unroll
        for (int r = 0; r < 4; ++r) {
            const int row = rb + r;
            if (row < NV) {
                float* po = out + (size_t)row * 64 + l15;
                #pragma unroll
                for (int n = 0; n < 4; ++n)
                    po[n << 4] = acc[m][n][r] + bv[n];
            }
        }
    }
}

// ---- fallback (round-1 kernel) if ws is too small for the bf16 staging ----
__global__ __launch_bounds__(256) void conv_gemm_kernel(
    const float* __restrict__ x, const int* __restrict__ neigh,
    const float* __restrict__ W, const float* __restrict__ bias,
    float* __restrict__ out)
{
    __shared__ unsigned Wl[56 * 64 * 4];
    const int t = threadIdx.x;
    for (int g = t; g < (64 * KTOT) / 4; g += 256) {
        int i = g << 2;
        int o = i / KTOT;
        int k = i - o * KTOT;
        const float4 w = *reinterpret_cast<const float4*>(W + i);
        unsigned p0 = pack2(w.x, w.y);
        unsigned p1 = pack2(w.z, w.w);
        unsigned* dst = &Wl[((((k >> 3) << 6) + o) << 2) + ((k & 7) >> 1)];
        *reinterpret_cast<uint2*>(dst) = make_uint2(p0, p1);
    }
    __syncthreads();

    const int wave = t >> 6, lane = t & 63;
    const int l15 = lane & 15, lg = lane >> 4;
    const int rowbase = blockIdx.x * 128 + wave * 32;
    const int row0 = rowbase + l15;
    const int row1 = row0 + 16;
    const int r0c = row0 < NV ? row0 : NV - 1;
    const int r1c = row1 < NV ? row1 : NV - 1;

    int idx0[7], idx1[7];
    #pragma unroll
    for (int j = 0; j < 7; ++j) {
        idx0[j] = neigh[r0c * 7 + j];
        idx1[j] = neigh[r1c * 7 + j];
    }

    f32x4 acc[2][4];
    #pragma unroll
    for (int m = 0; m < 2; ++m)
        #pragma unroll
        for (int n = 0; n < 4; ++n)
            acc[m][n] = (f32x4){0.f, 0.f, 0.f, 0.f};

    for (int j = 0; j < 7; ++j) {
        const float* p0 = x + (size_t)idx0[j] * 64;
        const float* p1 = x + (size_t)idx1[j] * 64;
        #pragma unroll
        for (int h = 0; h < 2; ++h) {
            const int foff = (h << 5) + (lg << 3);
            float4 a0lo = *reinterpret_cast<const float4*>(p0 + foff);
            float4 a0hi = *reinterpret_cast<const float4*>(p0 + foff + 4);
            float4 a1lo = *reinterpret_cast<const float4*>(p1 + foff);
            float4 a1hi = *reinterpret_cast<const float4*>(p1 + foff + 4);
            union { unsigned u[4]; bf16x8 v; } A0, A1;
            A0.u[0] = pack2(a0lo.x, a0lo.y); A0.u[1] = pack2(a0lo.z, a0lo.w);
            A0.u[2] = pack2(a0hi.x, a0hi.y); A0.u[3] = pack2(a0hi.z, a0hi.w);
            A1.u[0] = pack2(a1lo.x, a1lo.y); A1.u[1] = pack2(a1lo.z, a1lo.w);
            A1.u[2] = pack2(a1hi.x, a1hi.y); A1.u[3] = pack2(a1hi.z, a1hi.w);
            const int kq = (((j << 1) + h) << 2) + lg;
            #pragma unroll
            for (int n = 0; n < 4; ++n) {
                bf16x8 B = *reinterpret_cast<const bf16x8*>(
                    &Wl[((kq << 6) + (n << 4) + l15) << 2]);
                acc[0][n] = __builtin_amdgcn_mfma_f32_16x16x32_bf16(A0.v, B, acc[0][n], 0, 0, 0);
                acc[1][n] = __builtin_amdgcn_mfma_f32_16x16x32_bf16(A1.v, B, acc[1][n], 0, 0, 0);
            }
        }
    }

    float bv[4];
    #pragma unroll
    for (int n = 0; n < 4; ++n) bv[n] = bias[(n << 4) + l15];

    #pragma unroll
    for (int m = 0; m < 2; ++m) {
        const int rb = rowbase + (m << 4) + (lg << 2);
        #pragma unroll
        for (int r = 0; r < 4; ++r) {
            const int row = rb + r;
            if (row < NV) {
                float* po = out + (size_t)row * 64 + l15;
                #pragma unroll
                for (int n = 0; n < 4; ++n)
                    po[n << 4] = acc[m][n][r] + bv[n];
            }
        }
    }
}

extern "C" void kernel_launch(void* const* d_in, const int* in_sizes, int n_in,
                              void* d_out, int out_size, void* d_ws, size_t ws_size,
                              hipStream_t stream) {
    const float* x     = (const float*)d_in[0];
    const int*   neigh = (const int*)d_in[1];
    const float* W     = (const float*)d_in[2];
    const float* b     = (const float*)d_in[3];
    float* out = (float*)d_out;

    if (ws_size >= XB_BYTES + WB_BYTES) {
        unsigned char* ws = (unsigned char*)d_ws;
        const int prep_blocks = (XUNITS + WQUADS + 255) / 256;
        prep_kernel<<<dim3(prep_blocks), dim3(256), 0, stream>>>(x, W, ws);
        const uint4* xb = (const uint4*)ws;
        const uint4* Wb = (const uint4*)(ws + XB_BYTES);
        conv_gemm6<<<dim3(GRID6), dim3(768), 0, stream>>>(xb, neigh, Wb, b, out);
    } else {
        const int blocks = (NV + 127) / 128;   // 1281
        conv_gemm_kernel<<<dim3(blocks), dim3(256), 0, stream>>>(x, neigh, W, b, out);
    }
}

// Round 7
// 43.759 us; speedup vs baseline: 3.1249x; 1.0198x over previous
//
#include <hip/hip_runtime.h>
#include <hip/hip_bf16.h>

#define NV     163842
#define KTOT   448                 // 7 neighbors * 64 feats
#define KQ     56                  // KTOT/8 : 16B k-octs
#define WTILES 5121                // 32-row wave-tiles
#define GRID6  512                 // blocks (1/CU resident), 768 thr each
#define XUNITS (NV * 64 / 8)       // 1,310,736 16B units of bf16-x
#define WQUADS (64 * KTOT / 4)     // 7,168 float4 quads of W
#define XB_BYTES ((size_t)NV * 64 * 2)   // 20,971,776
#define WB_BYTES (KQ * 64 * 16)          // 57,344

typedef __attribute__((ext_vector_type(8))) short bf16x8;
typedef __attribute__((ext_vector_type(4))) float f32x4;

__device__ __forceinline__ unsigned f2bf(float f) {
    unsigned u = __builtin_bit_cast(unsigned, f);
    return (u + 0x7FFFu + ((u >> 16) & 1u)) >> 16;   // RNE truncate to bf16
}
__device__ __forceinline__ unsigned pack2(float a, float b) {
    return f2bf(a) | (f2bf(b) << 16);
}

// ---- prep: x f32 -> bf16 rows; W f32 -> bf16 fragment layout (+bank swizzle) ----
// W element (o,k): kq=k>>3, stored at 16B-unit u = kq*64 + (o ^ ((kq&3)<<1)),
// halfword k&7.
__global__ __launch_bounds__(256) void prep_kernel(
    const float* __restrict__ x, const float* __restrict__ W,
    unsigned char* __restrict__ ws)
{
    const int g = blockIdx.x * 256 + threadIdx.x;
    if (g < XUNITS) {
        const float4 lo = *reinterpret_cast<const float4*>(x + (size_t)g * 8);
        const float4 hi = *reinterpret_cast<const float4*>(x + (size_t)g * 8 + 4);
        uint4 u;
        u.x = pack2(lo.x, lo.y); u.y = pack2(lo.z, lo.w);
        u.z = pack2(hi.x, hi.y); u.w = pack2(hi.z, hi.w);
        *reinterpret_cast<uint4*>(ws + (size_t)g * 16) = u;
    } else if (g < XUNITS + WQUADS) {
        const int q = g - XUNITS;
        const int i = q << 2;              // i = o*448 + k, k%4==0
        const int o = i / KTOT;
        const int k = i - o * KTOT;
        const int kq = k >> 3;
        const int u = (kq << 6) + (o ^ ((kq & 3) << 1));
        const float4 w = *reinterpret_cast<const float4*>(W + i);
        uint2 p;
        p.x = pack2(w.x, w.y); p.y = pack2(w.z, w.w);
        *reinterpret_cast<uint2*>(ws + XB_BYTES + (size_t)u * 16 + (k & 7) * 2) = p;
    }
}

// ---- main GEMM: 512 blocks x 768 thr (12 waves), 1 block/CU.
// Wave w of block b owns 32-row tile (b + 512*w). ALL 28 gathers per wave
// are issued before the MFMA sequence (VGPR cap 170 via launch_bounds(768,3))
// to maximize outstanding scattered line requests per CU.
__global__ __launch_bounds__(768, 3) void conv_gemm7(
    const uint4* __restrict__ xb, const int* __restrict__ neigh,
    const uint4* __restrict__ Wb, const float* __restrict__ bias,
    float* __restrict__ out)
{
    __shared__ uint4 Wl[KQ * 64];          // 57,344 B
    const int t = threadIdx.x;
    const int wave = t >> 6, lane = t & 63;
    const int l15 = lane & 15, lg = lane >> 4;

    const int tile = blockIdx.x + GRID6 * wave;
    const bool work = tile < WTILES;

    // prefetch this tile's neighbor indices before the staging barrier
    int idx0[7], idx1[7];
    if (work) {
        const int rb = tile * 32;
        int r0 = rb + l15;      r0 = r0 < NV ? r0 : NV - 1;
        int r1 = rb + 16 + l15; r1 = r1 < NV ? r1 : NV - 1;
        #pragma unroll
        for (int j = 0; j < 7; ++j) {
            idx0[j] = neigh[r0 * 7 + j];
            idx1[j] = neigh[r1 * 7 + j];
        }
    }

    for (int u = t; u < KQ * 64; u += 768) Wl[u] = Wb[u];
    __syncthreads();

    if (!work) return;

    // ---- issue ALL 28 gathers up front (explicit constant indexing) ----
    uint4 ga[7][2], gb[7][2];
    #pragma unroll
    for (int j = 0; j < 7; ++j) {
        const uint4* p0 = xb + (size_t)idx0[j] * 8 + lg;
        const uint4* p1 = xb + (size_t)idx1[j] * 8 + lg;
        ga[j][0] = p0[0];   // feats 0..31, oct lg  (64B half-row, coalesced)
        ga[j][1] = p0[4];   // feats 32..63
        gb[j][0] = p1[0];
        gb[j][1] = p1[4];
    }

    const int sl15 = l15 ^ (lg << 1);      // read-side of the W bank swizzle
    const int rowbase = tile * 32;

    f32x4 acc[2][4];
    #pragma unroll
    for (int m = 0; m < 2; ++m)
        #pragma unroll
        for (int n = 0; n < 4; ++n)
            acc[m][n] = (f32x4){0.f, 0.f, 0.f, 0.f};

    #pragma unroll
    for (int j = 0; j < 7; ++j) {
        #pragma unroll
        for (int h = 0; h < 2; ++h) {
            const int kq = ((j * 2 + h) << 2) + lg;
            const int bbase = (kq << 6) + sl15;
            const bf16x8 A0 = __builtin_bit_cast(bf16x8, ga[j][h]);
            const bf16x8 A1 = __builtin_bit_cast(bf16x8, gb[j][h]);
            #pragma unroll
            for (int n = 0; n < 4; ++n) {
                const bf16x8 B = __builtin_bit_cast(bf16x8, Wl[bbase + (n << 4)]);
                acc[0][n] = __builtin_amdgcn_mfma_f32_16x16x32_bf16(A0, B, acc[0][n], 0, 0, 0);
                acc[1][n] = __builtin_amdgcn_mfma_f32_16x16x32_bf16(A1, B, acc[1][n], 0, 0, 0);
            }
        }
    }

    float bv[4];
    #pragma unroll
    for (int n = 0; n < 4; ++n) bv[n] = bias[(n << 4) + l15];

    // D layout: col = l15, row = lg*4 + r
    #pragma unroll
    for (int m = 0; m < 2; ++m) {
        const int rb = rowbase + (m << 4) + (lg << 2);
        #pragma unroll
        for (int r = 0; r < 4; ++r) {
            const int row = rb + r;
            if (row < NV) {
                float* po = out + (size_t)row * 64 + l15;
                #pragma unroll
                for (int n = 0; n < 4; ++n)
                    po[n << 4] = acc[m][n][r] + bv[n];
            }
        }
    }
}

// ---- fallback (round-1 kernel) if ws is too small for the bf16 staging ----
__global__ __launch_bounds__(256) void conv_gemm_kernel(
    const float* __restrict__ x, const int* __restrict__ neigh,
    const float* __restrict__ W, const float* __restrict__ bias,
    float* __restrict__ out)
{
    __shared__ unsigned Wl[56 * 64 * 4];
    const int t = threadIdx.x;
    for (int g = t; g < (64 * KTOT) / 4; g += 256) {
        int i = g << 2;
        int o = i / KTOT;
        int k = i - o * KTOT;
        const float4 w = *reinterpret_cast<const float4*>(W + i);
        unsigned p0 = pack2(w.x, w.y);
        unsigned p1 = pack2(w.z, w.w);
        unsigned* dst = &Wl[((((k >> 3) << 6) + o) << 2) + ((k & 7) >> 1)];
        *reinterpret_cast<uint2*>(dst) = make_uint2(p0, p1);
    }
    __syncthreads();

    const int wave = t >> 6, lane = t & 63;
    const int l15 = lane & 15, lg = lane >> 4;
    const int rowbase = blockIdx.x * 128 + wave * 32;
    const int row0 = rowbase + l15;
    const int row1 = row0 + 16;
    const int r0c = row0 < NV ? row0 : NV - 1;
    const int r1c = row1 < NV ? row1 : NV - 1;

    int idx0[7], idx1[7];
    #pragma unroll
    for (int j = 0; j < 7; ++j) {
        idx0[j] = neigh[r0c * 7 + j];
        idx1[j] = neigh[r1c * 7 + j];
    }

    f32x4 acc[2][4];
    #pragma unroll
    for (int m = 0; m < 2; ++m)
        #pragma unroll
        for (int n = 0; n < 4; ++n)
            acc[m][n] = (f32x4){0.f, 0.f, 0.f, 0.f};

    for (int j = 0; j < 7; ++j) {
        const float* p0 = x + (size_t)idx0[j] * 64;
        const float* p1 = x + (size_t)idx1[j] * 64;
        #pragma unroll
        for (int h = 0; h < 2; ++h) {
            const int foff = (h << 5) + (lg << 3);
            float4 a0lo = *reinterpret_cast<const float4*>(p0 + foff);
            float4 a0hi = *reinterpret_cast<const float4*>(p0 + foff + 4);
            float4 a1lo = *reinterpret_cast<const float4*>(p1 + foff);
            float4 a1hi = *reinterpret_cast<const float4*>(p1 + foff + 4);
            union { unsigned u[4]; bf16x8 v; } A0, A1;
            A0.u[0] = pack2(a0lo.x, a0lo.y); A0.u[1] = pack2(a0lo.z, a0lo.w);
            A0.u[2] = pack2(a0hi.x, a0hi.y); A0.u[3] = pack2(a0hi.z, a0hi.w);
            A1.u[0] = pack2(a1lo.x, a1lo.y); A1.u[1] = pack2(a1lo.z, a1lo.w);
            A1.u[2] = pack2(a1hi.x, a1hi.y); A1.u[3] = pack2(a1hi.z, a1hi.w);
            const int kq = (((j << 1) + h) << 2) + lg;
            #pragma unroll
            for (int n = 0; n < 4; ++n) {
                bf16x8 B = *reinterpret_cast<const bf16x8*>(
                    &Wl[((kq << 6) + (n << 4) + l15) << 2]);
                acc[0][n] = __builtin_amdgcn_mfma_f32_16x16x32_bf16(A0.v, B, acc[0][n], 0, 0, 0);
                acc[1][n] = __builtin_amdgcn_mfma_f32_16x16x32_bf16(A1.v, B, acc[1][n], 0, 0, 0);
            }
        }
    }

    float bv[4];
    #pragma unroll
    for (int n = 0; n < 4; ++n) bv[n] = bias[(n << 4) + l15];

    #pragma unroll
    for (int m = 0; m < 2; ++m) {
        const int rb = rowbase + (m << 4) + (lg << 2);
        #pragma unroll
        for (int r = 0; r < 4; ++r) {
            const int row = rb + r;
            if (row < NV) {
                float* po = out + (size_t)row * 64 + l15;
                #pragma unroll
                for (int n = 0; n < 4; ++n)
                    po[n << 4] = acc[m][n][r] + bv[n];
            }
        }
    }
}

extern "C" void kernel_launch(void* const* d_in, const int* in_sizes, int n_in,
                              void* d_out, int out_size, void* d_ws, size_t ws_size,
                              hipStream_t stream) {
    const float* x     = (const float*)d_in[0];
    const int*   neigh = (const int*)d_in[1];
    const float* W     = (const float*)d_in[2];
    const float* b     = (const float*)d_in[3];
    float* out = (float*)d_out;

    if (ws_size >= XB_BYTES + WB_BYTES) {
        unsigned char* ws = (unsigned char*)d_ws;
        const int prep_blocks = (XUNITS + WQUADS + 255) / 256;
        prep_kernel<<<dim3(prep_blocks), dim3(256), 0, stream>>>(x, W, ws);
        const uint4* xb = (const uint4*)ws;
        const uint4* Wb = (const uint4*)(ws + XB_BYTES);
        conv_gemm7<<<dim3(GRID6), dim3(768), 0, stream>>>(xb, neigh, Wb, b, out);
    } else {
        const int blocks = (NV + 127) / 128;   // 1281
        conv_gemm_kernel<<<dim3(blocks), dim3(256), 0, stream>>>(x, neigh, W, b, out);
    }
}